// Round 2
// baseline (37231.473 us; speedup 1.0000x reference)
//
#include <hip/hip_runtime.h>

// Problem constants
#define Bn   512
#define Tn   1024
#define Fn   64
#define Hn   512
#define NBLK 288
// K for both layers = 576 (64+512 and 512+64), 18 k-blocks of 32

typedef short bf16x8 __attribute__((ext_vector_type(8)));
typedef float f32x4  __attribute__((ext_vector_type(4)));

__device__ __forceinline__ short f2bf(float f) {
    union { float f; unsigned u; } v; v.f = f;
    unsigned r = (v.u + 0x7FFFu + ((v.u >> 16) & 1u)) >> 16;  // RNE
    return (short)(unsigned short)r;
}
__device__ __forceinline__ float sigm(float x) { return 1.f / (1.f + __expf(-x)); }
__device__ __forceinline__ float tanh_(float x) { return 2.f / (1.f + __expf(-2.f * x)) - 1.f; }

__device__ __forceinline__ bf16x8 cvt8(const float* p) {
    const float4 v0 = *(const float4*)p;
    const float4 v1 = *(const float4*)(p + 4);
    bf16x8 a;
    a[0] = f2bf(v0.x); a[1] = f2bf(v0.y); a[2] = f2bf(v0.z); a[3] = f2bf(v0.w);
    a[4] = f2bf(v1.x); a[5] = f2bf(v1.y); a[6] = f2bf(v1.z); a[7] = f2bf(v1.w);
    return a;
}

// Device-scope grid barrier. Each block calls with a monotonically increasing
// `target` (1,2,3,...). Arrive: fetch_add on cnt; last arrival resets cnt and
// release-stores gen = target; others spin on acquire-load gen >= target.
// Bounded spin: if co-residency ever fails we produce wrong results, not a hang.
__device__ __forceinline__ void grid_barrier(unsigned* cnt, unsigned* gen, unsigned target) {
    __syncthreads();
    if (threadIdx.x == 0) {
        unsigned a = __hip_atomic_fetch_add(cnt, 1u, __ATOMIC_ACQ_REL, __HIP_MEMORY_SCOPE_AGENT);
        if (a == NBLK - 1u) {
            __hip_atomic_store(cnt, 0u, __ATOMIC_RELAXED, __HIP_MEMORY_SCOPE_AGENT);
            __hip_atomic_store(gen, target, __ATOMIC_RELEASE, __HIP_MEMORY_SCOPE_AGENT);
        } else {
            long spins = 0;
            while (__hip_atomic_load(gen, __ATOMIC_ACQUIRE, __HIP_MEMORY_SCOPE_AGENT) < target) {
                __builtin_amdgcn_s_sleep(1);
                if (++spins > (1L << 28)) break;  // ~seconds; safety valve only
            }
        }
    }
    __syncthreads();
}

// ---------------- prepack: zero states/barrier, bias sums, weights -> bf16 frag order ----------------
// w1f layout: [ut 32][kb 18][gate 4][n 16][kk 32]  (gcol = gate*512 + ut*16 + n, k = kb*32+kk)
// w2f layout: [ut4 4][kb 18][gate 4][n 16][kk 32]  (gcol = gate*64 + ut4*16 + n)
__global__ void prep_kernel(const float* __restrict__ Wih1, const float* __restrict__ Whh1,
                            const float* __restrict__ Wih2, const float* __restrict__ Whh2,
                            const float* __restrict__ bih1, const float* __restrict__ bhh1,
                            const float* __restrict__ bih2, const float* __restrict__ bhh2,
                            short* __restrict__ h1g, short* __restrict__ h2g,
                            short* __restrict__ w1f, short* __restrict__ w2f,
                            float* __restrict__ bs1, float* __restrict__ bs2,
                            unsigned* __restrict__ bar) {
    const int i0 = blockIdx.x * blockDim.x + threadIdx.x;
    const int stride = gridDim.x * blockDim.x;
    for (int i = i0; i < 128; i += stride) bar[i] = 0;                 // barrier cnt/gen
    for (int i = i0; i < 2 * Bn * Hn; i += stride) h1g[i] = 0;         // both h1 buffers
    for (int i = i0; i < 2 * Bn * Fn; i += stride) h2g[i] = 0;         // both h2 buffers
    for (int i = i0; i < 2048 * 576; i += stride) {                    // w1f pack
        int kk = i & 31, n = (i >> 5) & 15, ct = (i >> 9) & 3;
        int r = i >> 11; int kb = r % 18; int ut = r / 18;
        int gcol = ct * 512 + ut * 16 + n;
        int k = kb * 32 + kk;
        float v = (k < 64) ? Wih1[gcol * 64 + k] : Whh1[gcol * 512 + (k - 64)];
        w1f[i] = f2bf(v);
    }
    for (int i = i0; i < 256 * 576; i += stride) {                     // w2f pack
        int kk = i & 31, n = (i >> 5) & 15, ct = (i >> 9) & 3;
        int r = i >> 11; int kb = r % 18; int ut4 = r / 18;
        int gcol = ct * 64 + ut4 * 16 + n;
        int k = kb * 32 + kk;
        float v = (k < 512) ? Wih2[gcol * 512 + k] : Whh2[gcol * 64 + (k - 512)];
        w2f[i] = f2bf(v);
    }
    for (int i = i0; i < 2048; i += stride) bs1[i] = bih1[i] + bhh1[i];
    for (int i = i0; i < 256;  i += stride) bs2[i] = bih2[i] + bhh2[i];
}

// ---------------- main persistent kernel (regular launch + software barrier) ----------------
// 288 blocks x 128 threads. Blocks 0..255: LSTM1 (8 row-tiles x 32 unit-tiles).
// Blocks 256..287: LSTM2 (8 row-tiles x 4 unit-tiles). One barrier per step.
//   lstm1 role: { step(t); barrier(t+1); }  -> step(t) in window t
//   lstm2 role: { barrier(t+1); step(t); }  -> step(t) in window t+1, overlapped with lstm1 step(t+1)
// Buffers: h1g[t&1] read / h1g[(t+1)&1] write; c1g[t&1] written by lstm1(t), read by lstm2(t);
//          h2g[t&1] read / h2g[(t+1)&1] write by lstm2(t). All races separated by >=1 barrier.
__global__ __launch_bounds__(128) void lstm_kernel(
    const float* __restrict__ data,
    const short* __restrict__ w1f, const float* __restrict__ bs1,
    const short* __restrict__ w2f, const float* __restrict__ bs2,
    short* __restrict__ h1g, short* __restrict__ c1g, short* __restrict__ h2g,
    float* __restrict__ out, unsigned* __restrict__ bar) {
    unsigned* bcnt = bar;
    unsigned* bgen = bar + 64;  // 256 B apart — separate cachelines
    const int tid = threadIdx.x;
    const int lane = tid & 63, wv = tid >> 6;
    const int n = lane & 15, q = lane >> 4;
    const int bid = blockIdx.x;
    const f32x4 Z4 = {0.f, 0.f, 0.f, 0.f};

    if (bid < 256) {
        // ---------------- LSTM1 ----------------
        const int rt = bid >> 5, ut = bid & 31;
        const int rowbase = rt * 64 + wv * 32;
        const int ucol = ut * 16 + n;
        const float bi_ = bs1[ucol], bf_ = bs1[512 + ucol], bg_ = bs1[1024 + ucol], bo_ = bs1[1536 + ucol];
        const short* wbase = w1f + ut * 36864 + n * 32 + q * 8;
        const int r0 = rowbase + n, r1 = rowbase + 16 + n;
        f32x4 c1f[2]; c1f[0] = Z4; c1f[1] = Z4;

        for (int t = 0; t < Tn; ++t) {
            const short* h1r = h1g + (t & 1) * (Bn * Hn);
            short* h1w = h1g + ((t + 1) & 1) * (Bn * Hn);
            short* c1w = c1g + (t & 1) * (Bn * Hn);
            f32x4 acc[2][4];
#pragma unroll
            for (int a = 0; a < 2; ++a)
#pragma unroll
                for (int g = 0; g < 4; ++g) acc[a][g] = Z4;

            const float* x0 = data + (size_t)r0 * 65536 + t * 64;
            const float* x1 = data + (size_t)r1 * 65536 + t * 64;
#pragma unroll
            for (int kb = 0; kb < 18; ++kb) {
                bf16x8 a0, a1;
                if (kb < 2) {
                    a0 = cvt8(x0 + kb * 32 + q * 8);
                    a1 = cvt8(x1 + kb * 32 + q * 8);
                } else {
                    const int k = kb * 32 + q * 8 - 64;
                    a0 = *(const bf16x8*)(h1r + r0 * 512 + k);
                    a1 = *(const bf16x8*)(h1r + r1 * 512 + k);
                }
#pragma unroll
                for (int g = 0; g < 4; ++g) {
                    const bf16x8 b = *(const bf16x8*)(wbase + (kb * 4 + g) * 512);
                    acc[0][g] = __builtin_amdgcn_mfma_f32_16x16x32_bf16(a0, b, acc[0][g], 0, 0, 0);
                    acc[1][g] = __builtin_amdgcn_mfma_f32_16x16x32_bf16(a1, b, acc[1][g], 0, 0, 0);
                }
            }
            // epilogue: gates + state update. C-frag: col = lane&15 (= unit), row = q*4 + reg
#pragma unroll
            for (int rt16 = 0; rt16 < 2; ++rt16) {
#pragma unroll
                for (int r = 0; r < 4; ++r) {
                    const float xi = acc[rt16][0][r] + bi_;
                    const float xf = acc[rt16][1][r] + bf_;
                    const float xg = acc[rt16][2][r] + bg_;
                    const float xo = acc[rt16][3][r] + bo_;
                    const float ii = sigm(xi), ff = sigm(xf), gg = tanh_(xg), oo = sigm(xo);
                    const float c = ff * c1f[rt16][r] + ii * gg;
                    c1f[rt16][r] = c;
                    const float h = oo * tanh_(c);
                    const int row = rowbase + rt16 * 16 + q * 4 + r;
                    h1w[row * 512 + ucol] = f2bf(h);
                    c1w[row * 512 + ucol] = f2bf(c);
                }
            }
            grid_barrier(bcnt, bgen, (unsigned)(t + 1));
        }
    } else {
        // ---------------- LSTM2 ----------------
        const int b2 = bid - 256;
        const int rt2 = b2 >> 2, ut4 = b2 & 3;
        const int rowbase = rt2 * 64 + wv * 32;
        const int ucol = ut4 * 16 + n;
        const float bi_ = bs2[ucol], bf_ = bs2[64 + ucol], bg_ = bs2[128 + ucol], bo_ = bs2[192 + ucol];
        const short* wbase = w2f + ut4 * 36864 + n * 32 + q * 8;
        const int r0 = rowbase + n, r1 = rowbase + 16 + n;
        f32x4 c2f[2]; c2f[0] = Z4; c2f[1] = Z4;

        for (int t = 0; t < Tn; ++t) {
            grid_barrier(bcnt, bgen, (unsigned)(t + 1));  // wait for lstm1(t) -> c1(t)
            const short* c1r = c1g + (t & 1) * (Bn * Hn);
            const short* h2r = h2g + (t & 1) * (Bn * Fn);
            short* h2w = h2g + ((t + 1) & 1) * (Bn * Fn);
            f32x4 acc[2][4];
#pragma unroll
            for (int a = 0; a < 2; ++a)
#pragma unroll
                for (int g = 0; g < 4; ++g) acc[a][g] = Z4;

#pragma unroll
            for (int kb = 0; kb < 18; ++kb) {
                bf16x8 a0, a1;
                if (kb < 16) {
                    const int k = kb * 32 + q * 8;
                    a0 = *(const bf16x8*)(c1r + r0 * 512 + k);
                    a1 = *(const bf16x8*)(c1r + r1 * 512 + k);
                } else {
                    const int k = (kb - 16) * 32 + q * 8;
                    a0 = *(const bf16x8*)(h2r + r0 * 64 + k);
                    a1 = *(const bf16x8*)(h2r + r1 * 64 + k);
                }
#pragma unroll
                for (int g = 0; g < 4; ++g) {
                    const bf16x8 b = *(const bf16x8*)(wbase + (kb * 4 + g) * 512);
                    acc[0][g] = __builtin_amdgcn_mfma_f32_16x16x32_bf16(a0, b, acc[0][g], 0, 0, 0);
                    acc[1][g] = __builtin_amdgcn_mfma_f32_16x16x32_bf16(a1, b, acc[1][g], 0, 0, 0);
                }
            }
#pragma unroll
            for (int rt16 = 0; rt16 < 2; ++rt16) {
#pragma unroll
                for (int r = 0; r < 4; ++r) {
                    const float xi = acc[rt16][0][r] + bi_;
                    const float xf = acc[rt16][1][r] + bf_;
                    const float xg = acc[rt16][2][r] + bg_;
                    const float xo = acc[rt16][3][r] + bo_;
                    const float ii = sigm(xi), ff = sigm(xf), gg = tanh_(xg), oo = sigm(xo);
                    const float c = ff * c2f[rt16][r] + ii * gg;
                    c2f[rt16][r] = c;
                    const float h = oo * tanh_(c);
                    const int row = rowbase + rt16 * 16 + q * 4 + r;
                    out[(size_t)row * 65536 + (size_t)t * 64 + ucol] = c;  // output is c2
                    h2w[row * 64 + ucol] = f2bf(h);
                }
            }
        }
    }
}

extern "C" void kernel_launch(void* const* d_in, const int* in_sizes, int n_in,
                              void* d_out, int out_size, void* d_ws, size_t ws_size,
                              hipStream_t stream) {
    const float* data = (const float*)d_in[0];
    const float* Wih1 = (const float*)d_in[1];
    const float* Whh1 = (const float*)d_in[2];
    const float* bih1 = (const float*)d_in[3];
    const float* bhh1 = (const float*)d_in[4];
    const float* Wih2 = (const float*)d_in[5];
    const float* Whh2 = (const float*)d_in[6];
    const float* bih2 = (const float*)d_in[7];
    const float* bhh2 = (const float*)d_in[8];
    float* out = (float*)d_out;

    char* w = (char*)d_ws;
    short* h1g = (short*)(w + 0);          // 2 * 512*512*2 = 1,048,576
    short* c1g = (short*)(w + 1048576);    // 1,048,576
    short* h2g = (short*)(w + 2097152);    // 2 * 512*64*2 = 131,072
    short* w2f = (short*)(w + 2228224);    // 256*576*2 = 294,912
    short* w1f = (short*)(w + 2523136);    // 2048*576*2 = 2,359,296
    float* bs1 = (float*)(w + 4882432);    // 8,192
    float* bs2 = (float*)(w + 4890624);    // 1,024
    unsigned* bar = (unsigned*)(w + 4891648); // 512 B barrier state

    hipLaunchKernelGGL(prep_kernel, dim3(1024), dim3(256), 0, stream,
                       Wih1, Whh1, Wih2, Whh2, bih1, bhh1, bih2, bhh2,
                       h1g, h2g, w1f, w2f, bs1, bs2, bar);

    hipLaunchKernelGGL(lstm_kernel, dim3(NBLK), dim3(128), 0, stream,
                       data, w1f, bs1, w2f, bs2, h1g, c1g, h2g, out, bar);
}

// Round 3
// 15152.237 us; speedup vs baseline: 2.4572x; 2.4572x over previous
//
#include <hip/hip_runtime.h>

// Problem constants
#define Bn   512
#define Tn   1024
#define Fn   64
#define Hn   512
#define NB1  128                 // LSTM1 blocks: 8 rt x 16 utp
#define NB2  16                  // LSTM2 blocks: 8 rt x 2 u2
#define NBLK (NB1 + NB2)
#define GMEM 18                  // barrier members per rt group: 16 + 2

typedef short bf16x8 __attribute__((ext_vector_type(8)));
typedef float f32x4  __attribute__((ext_vector_type(4)));

__device__ __forceinline__ short f2bf(float f) {
    union { float f; unsigned u; } v; v.f = f;
    unsigned r = (v.u + 0x7FFFu + ((v.u >> 16) & 1u)) >> 16;  // RNE
    return (short)(unsigned short)r;
}
__device__ __forceinline__ float sigm(float x) { return 1.f / (1.f + __expf(-x)); }
__device__ __forceinline__ float tanh_(float x) { return 2.f / (1.f + __expf(-2.f * x)) - 1.f; }

__device__ __forceinline__ bf16x8 cvt8(const float* p) {
    const float4 v0 = *(const float4*)p;
    const float4 v1 = *(const float4*)(p + 4);
    bf16x8 a;
    a[0] = f2bf(v0.x); a[1] = f2bf(v0.y); a[2] = f2bf(v0.z); a[3] = f2bf(v0.w);
    a[4] = f2bf(v1.x); a[5] = f2bf(v1.y); a[6] = f2bf(v1.z); a[7] = f2bf(v1.w);
    return a;
}

// -------- device-coherent (MALL-level) state exchange: relaxed agent atomics --------
// These bypass the (non-coherent) per-XCD L2 entirely, so NO acquire/invalidate is
// ever needed, and the L2-cached weights/x stay resident across all 1024 steps.
__device__ __forceinline__ unsigned long long ld64(const short* p) {
    return __hip_atomic_load((const unsigned long long*)p, __ATOMIC_RELAXED, __HIP_MEMORY_SCOPE_AGENT);
}
__device__ __forceinline__ bf16x8 ld16B(const short* p) {
    union { unsigned long long u[2]; bf16x8 v; } x;
    x.u[0] = ld64(p);
    x.u[1] = ld64(p + 4);
    return x.v;
}
__device__ __forceinline__ void st2(short* p, short v) {
    __hip_atomic_store((unsigned short*)p, (unsigned short)v, __ATOMIC_RELAXED, __HIP_MEMORY_SCOPE_AGENT);
}

// Per-group barrier. Arrive with RELEASE (orders this block's write-through state
// stores: vmcnt(0) + cheap wbl2). Spin with RELAXED (no L2 invalidate!). Consumer
// reads use L2-bypassing atomics, so no acquire fence is required.
__device__ __forceinline__ void group_barrier(unsigned* cnt, unsigned* gen, unsigned target) {
    __syncthreads();
    if (threadIdx.x == 0) {
        unsigned a = __hip_atomic_fetch_add(cnt, 1u, __ATOMIC_RELEASE, __HIP_MEMORY_SCOPE_AGENT);
        if (a == GMEM - 1u) {
            __hip_atomic_store(cnt, 0u, __ATOMIC_RELAXED, __HIP_MEMORY_SCOPE_AGENT);
            __hip_atomic_store(gen, target, __ATOMIC_RELEASE, __HIP_MEMORY_SCOPE_AGENT);
        } else {
            long spins = 0;
            while (__hip_atomic_load(gen, __ATOMIC_RELAXED, __HIP_MEMORY_SCOPE_AGENT) < target) {
                __builtin_amdgcn_s_sleep(1);
                if (++spins > (1L << 22)) break;  // safety valve
            }
            __atomic_signal_fence(__ATOMIC_ACQUIRE);
        }
    }
    __syncthreads();
}

// ---------------- prepack (unchanged layouts) ----------------
// w1f: [ut 32][kb 18][gate 4][n 16][kk 32]  (gcol = gate*512 + ut*16 + n, k = kb*32+kk)
// w2f: [ut4 4][kb 18][gate 4][n 16][kk 32]  (gcol = gate*64 + ut4*16 + n)
__global__ void prep_kernel(const float* __restrict__ Wih1, const float* __restrict__ Whh1,
                            const float* __restrict__ Wih2, const float* __restrict__ Whh2,
                            const float* __restrict__ bih1, const float* __restrict__ bhh1,
                            const float* __restrict__ bih2, const float* __restrict__ bhh2,
                            short* __restrict__ h1g, short* __restrict__ h2g,
                            short* __restrict__ w1f, short* __restrict__ w2f,
                            float* __restrict__ bs1, float* __restrict__ bs2,
                            unsigned* __restrict__ bar) {
    const int i0 = blockIdx.x * blockDim.x + threadIdx.x;
    const int stride = gridDim.x * blockDim.x;
    for (int i = i0; i < 1024; i += stride) bar[i] = 0;                // 8 groups x 128
    for (int i = i0; i < 2 * Bn * Hn; i += stride) h1g[i] = 0;
    for (int i = i0; i < 2 * Bn * Fn; i += stride) h2g[i] = 0;
    for (int i = i0; i < 2048 * 576; i += stride) {
        int kk = i & 31, n = (i >> 5) & 15, ct = (i >> 9) & 3;
        int r = i >> 11; int kb = r % 18; int ut = r / 18;
        int gcol = ct * 512 + ut * 16 + n;
        int k = kb * 32 + kk;
        float v = (k < 64) ? Wih1[gcol * 64 + k] : Whh1[gcol * 512 + (k - 64)];
        w1f[i] = f2bf(v);
    }
    for (int i = i0; i < 256 * 576; i += stride) {
        int kk = i & 31, n = (i >> 5) & 15, ct = (i >> 9) & 3;
        int r = i >> 11; int kb = r % 18; int ut4 = r / 18;
        int gcol = ct * 64 + ut4 * 16 + n;
        int k = kb * 32 + kk;
        float v = (k < 512) ? Wih2[gcol * 512 + k] : Whh2[gcol * 64 + (k - 512)];
        w2f[i] = f2bf(v);
    }
    for (int i = i0; i < 2048; i += stride) bs1[i] = bih1[i] + bhh1[i];
    for (int i = i0; i < 256;  i += stride) bs2[i] = bih2[i] + bhh2[i];
}

// ---------------- main persistent kernel ----------------
// 144 blocks x 256 threads (4 waves), 1 block/CU, 1 wave/SIMD -> 512-VGPR budget.
// Waves: wvr = wv&1 (row half: 32 rows), wvc = wv>>1 (col half: one 16-unit tile).
// LSTM1 block (rt, utp): rows rt*64..+63, units (utp*2+wvc)*16..+15, all 4 gates.
// LSTM2 block (rt2, u2): rows rt2*64..+63, units (u2*2+wvc)*16..+15.
// Recurrent weights live in VGPRs (16 kb x 4 gates x bf16x8 = 256 VGPR/lane);
// the remaining 2 k-blocks stream from L2 (never invalidated now).
__global__ __launch_bounds__(256, 1) void lstm_kernel(
    const float* __restrict__ data,
    const short* __restrict__ w1f, const float* __restrict__ bs1,
    const short* __restrict__ w2f, const float* __restrict__ bs2,
    short* __restrict__ h1g, short* __restrict__ c1g, short* __restrict__ h2g,
    float* __restrict__ out, unsigned* __restrict__ bar) {
    const int tid = threadIdx.x;
    const int lane = tid & 63, wv = tid >> 6;
    const int n = lane & 15, q = lane >> 4;
    const int wvr = wv & 1, wvc = wv >> 1;
    const int bid = blockIdx.x;
    const f32x4 Z4 = {0.f, 0.f, 0.f, 0.f};

    if (bid < NB1) {
        // ---------------- LSTM1 ----------------
        const int rt = bid >> 4, utp = bid & 15;
        const int ut = utp * 2 + wvc;
        const int rowbase = rt * 64 + wvr * 32;
        const int ucol = ut * 16 + n;
        unsigned* bcnt = bar + rt * 128;
        unsigned* bgen = bar + rt * 128 + 64;
        const float bi_ = bs1[ucol], bf_ = bs1[512 + ucol], bg_ = bs1[1024 + ucol], bo_ = bs1[1536 + ucol];
        const short* wbase = w1f + ut * 36864 + n * 32 + q * 8;
        const int r0 = rowbase + n, r1 = rowbase + 16 + n;

        // recurrent weights (kb 2..17) -> registers, once
        bf16x8 wr[16][4];
#pragma unroll
        for (int kb = 0; kb < 16; ++kb)
#pragma unroll
            for (int g = 0; g < 4; ++g)
                wr[kb][g] = *(const bf16x8*)(wbase + ((kb + 2) * 4 + g) * 512);

        f32x4 c1f[2]; c1f[0] = Z4; c1f[1] = Z4;

        for (int t = 0; t < Tn; ++t) {
            const short* h1r = h1g + (t & 1) * (Bn * Hn);
            short* h1w = h1g + ((t + 1) & 1) * (Bn * Hn);
            short* c1w = c1g + (t & 1) * (Bn * Hn);
            f32x4 acc[2][4];
#pragma unroll
            for (int a = 0; a < 2; ++a)
#pragma unroll
                for (int g = 0; g < 4; ++g) acc[a][g] = Z4;

            const float* x0 = data + (size_t)r0 * 65536 + t * 64;
            const float* x1 = data + (size_t)r1 * 65536 + t * 64;
            // x part (kb 0,1): streamed weights from L2, x from L2
#pragma unroll
            for (int kb = 0; kb < 2; ++kb) {
                const bf16x8 a0 = cvt8(x0 + kb * 32 + q * 8);
                const bf16x8 a1 = cvt8(x1 + kb * 32 + q * 8);
#pragma unroll
                for (int g = 0; g < 4; ++g) {
                    const bf16x8 b = *(const bf16x8*)(wbase + (kb * 4 + g) * 512);
                    acc[0][g] = __builtin_amdgcn_mfma_f32_16x16x32_bf16(a0, b, acc[0][g], 0, 0, 0);
                    acc[1][g] = __builtin_amdgcn_mfma_f32_16x16x32_bf16(a1, b, acc[1][g], 0, 0, 0);
                }
            }
            // h part (kb 2..17): A via MALL-coherent loads, B from registers
#pragma unroll
            for (int kb = 0; kb < 16; ++kb) {
                const int k = kb * 32 + q * 8;
                const bf16x8 a0 = ld16B(h1r + r0 * 512 + k);
                const bf16x8 a1 = ld16B(h1r + r1 * 512 + k);
#pragma unroll
                for (int g = 0; g < 4; ++g) {
                    acc[0][g] = __builtin_amdgcn_mfma_f32_16x16x32_bf16(a0, wr[kb][g], acc[0][g], 0, 0, 0);
                    acc[1][g] = __builtin_amdgcn_mfma_f32_16x16x32_bf16(a1, wr[kb][g], acc[1][g], 0, 0, 0);
                }
            }
            // epilogue: C-frag col = lane&15 (unit), row = q*4 + reg
#pragma unroll
            for (int rt16 = 0; rt16 < 2; ++rt16) {
#pragma unroll
                for (int r = 0; r < 4; ++r) {
                    const float xi = acc[rt16][0][r] + bi_;
                    const float xf = acc[rt16][1][r] + bf_;
                    const float xg = acc[rt16][2][r] + bg_;
                    const float xo = acc[rt16][3][r] + bo_;
                    const float ii = sigm(xi), ff = sigm(xf), gg = tanh_(xg), oo = sigm(xo);
                    const float c = ff * c1f[rt16][r] + ii * gg;
                    c1f[rt16][r] = c;
                    const float h = oo * tanh_(c);
                    const int row = rowbase + rt16 * 16 + q * 4 + r;
                    st2(h1w + row * 512 + ucol, f2bf(h));
                    st2(c1w + row * 512 + ucol, f2bf(c));
                }
            }
            group_barrier(bcnt, bgen, (unsigned)(t + 1));
        }
    } else {
        // ---------------- LSTM2 ----------------
        const int b2 = bid - NB1;
        const int rt2 = b2 >> 1, u2 = b2 & 1;
        const int ut4 = u2 * 2 + wvc;
        const int rowbase = rt2 * 64 + wvr * 32;
        const int ucol = ut4 * 16 + n;
        unsigned* bcnt = bar + rt2 * 128;
        unsigned* bgen = bar + rt2 * 128 + 64;
        const float bi_ = bs2[ucol], bf_ = bs2[64 + ucol], bg_ = bs2[128 + ucol], bo_ = bs2[192 + ucol];
        const short* wbase = w2f + ut4 * 36864 + n * 32 + q * 8;
        const int r0 = rowbase + n, r1 = rowbase + 16 + n;

        // c1-part weights (kb 0..15) -> registers
        bf16x8 wr[16][4];
#pragma unroll
        for (int kb = 0; kb < 16; ++kb)
#pragma unroll
            for (int g = 0; g < 4; ++g)
                wr[kb][g] = *(const bf16x8*)(wbase + (kb * 4 + g) * 512);

        f32x4 c2f[2]; c2f[0] = Z4; c2f[1] = Z4;

        for (int t = 0; t < Tn; ++t) {
            group_barrier(bcnt, bgen, (unsigned)(t + 1));  // wait for c1(t)
            const short* c1r = c1g + (t & 1) * (Bn * Hn);
            const short* h2r = h2g + (t & 1) * (Bn * Fn);
            short* h2w = h2g + ((t + 1) & 1) * (Bn * Fn);
            f32x4 acc[2][4];
#pragma unroll
            for (int a = 0; a < 2; ++a)
#pragma unroll
                for (int g = 0; g < 4; ++g) acc[a][g] = Z4;

#pragma unroll
            for (int kb = 0; kb < 16; ++kb) {
                const int k = kb * 32 + q * 8;
                const bf16x8 a0 = ld16B(c1r + r0 * 512 + k);
                const bf16x8 a1 = ld16B(c1r + r1 * 512 + k);
#pragma unroll
                for (int g = 0; g < 4; ++g) {
                    acc[0][g] = __builtin_amdgcn_mfma_f32_16x16x32_bf16(a0, wr[kb][g], acc[0][g], 0, 0, 0);
                    acc[1][g] = __builtin_amdgcn_mfma_f32_16x16x32_bf16(a1, wr[kb][g], acc[1][g], 0, 0, 0);
                }
            }
#pragma unroll
            for (int kb = 16; kb < 18; ++kb) {
                const int k = (kb - 16) * 32 + q * 8;
                const bf16x8 a0 = ld16B(h2r + r0 * 64 + k);
                const bf16x8 a1 = ld16B(h2r + r1 * 64 + k);
#pragma unroll
                for (int g = 0; g < 4; ++g) {
                    const bf16x8 b = *(const bf16x8*)(wbase + (kb * 4 + g) * 512);
                    acc[0][g] = __builtin_amdgcn_mfma_f32_16x16x32_bf16(a0, b, acc[0][g], 0, 0, 0);
                    acc[1][g] = __builtin_amdgcn_mfma_f32_16x16x32_bf16(a1, b, acc[1][g], 0, 0, 0);
                }
            }
#pragma unroll
            for (int rt16 = 0; rt16 < 2; ++rt16) {
#pragma unroll
                for (int r = 0; r < 4; ++r) {
                    const float xi = acc[rt16][0][r] + bi_;
                    const float xf = acc[rt16][1][r] + bf_;
                    const float xg = acc[rt16][2][r] + bg_;
                    const float xo = acc[rt16][3][r] + bo_;
                    const float ii = sigm(xi), ff = sigm(xf), gg = tanh_(xg), oo = sigm(xo);
                    const float c = ff * c2f[rt16][r] + ii * gg;
                    c2f[rt16][r] = c;
                    const float h = oo * tanh_(c);
                    const int row = rowbase + rt16 * 16 + q * 4 + r;
                    out[(size_t)row * 65536 + (size_t)t * 64 + ucol] = c;  // output is c2
                    st2(h2w + row * 64 + ucol, f2bf(h));
                }
            }
        }
    }
}

extern "C" void kernel_launch(void* const* d_in, const int* in_sizes, int n_in,
                              void* d_out, int out_size, void* d_ws, size_t ws_size,
                              hipStream_t stream) {
    const float* data = (const float*)d_in[0];
    const float* Wih1 = (const float*)d_in[1];
    const float* Whh1 = (const float*)d_in[2];
    const float* bih1 = (const float*)d_in[3];
    const float* bhh1 = (const float*)d_in[4];
    const float* Wih2 = (const float*)d_in[5];
    const float* Whh2 = (const float*)d_in[6];
    const float* bih2 = (const float*)d_in[7];
    const float* bhh2 = (const float*)d_in[8];
    float* out = (float*)d_out;

    char* w = (char*)d_ws;
    short* h1g = (short*)(w + 0);          // 2 * 512*512*2 = 1,048,576
    short* c1g = (short*)(w + 1048576);    // 1,048,576
    short* h2g = (short*)(w + 2097152);    // 2 * 512*64*2 = 131,072
    short* w2f = (short*)(w + 2228224);    // 256*576*2 = 294,912
    short* w1f = (short*)(w + 2523136);    // 2048*576*2 = 2,359,296
    float* bs1 = (float*)(w + 4882432);    // 8,192
    float* bs2 = (float*)(w + 4890624);    // 1,024
    unsigned* bar = (unsigned*)(w + 4891648); // 4 KB: 8 groups x 512 B

    hipLaunchKernelGGL(prep_kernel, dim3(1024), dim3(256), 0, stream,
                       Wih1, Whh1, Wih2, Whh2, bih1, bhh1, bih2, bhh2,
                       h1g, h2g, w1f, w2f, bs1, bs2, bar);

    hipLaunchKernelGGL(lstm_kernel, dim3(NBLK), dim3(256), 0, stream,
                       data, w1f, bs1, w2f, bs2, h1g, c1g, h2g, out, bar);
}